// Round 1
// baseline (813.294 us; speedup 1.0000x reference)
//
#include <hip/hip_runtime.h>
#include <cstdint>

#define T_SEQ 2048
#define HID   4096
#define NH    32
#define HD    128
#define QKVW  12288   // (32 + 2*32) * 128

typedef float  f32x4  __attribute__((ext_vector_type(4)));
typedef __bf16 bf16x8 __attribute__((ext_vector_type(8)));

// log2(e)/sqrt(128): fold softmax scale + base-2 conversion into Q
#define QSCALE (0.08838834764831845f * 1.4426950408889634f)

__device__ __forceinline__ unsigned short f2bf(float f) {
  unsigned int u = __builtin_bit_cast(unsigned int, f);
  u += 0x7fffu + ((u >> 16) & 1u);          // round-to-nearest-even (inputs finite)
  return (unsigned short)(u >> 16);
}

// async global->LDS, 16B per lane. LDS dest is wave-uniform base + lane*16.
__device__ __forceinline__ void gload_lds16(const void* gptr, void* lptr) {
  __builtin_amdgcn_global_load_lds(
      (const __attribute__((address_space(1))) unsigned int*)(unsigned long long)(uintptr_t)gptr,
      (__attribute__((address_space(3))) unsigned int*)(unsigned int)(uintptr_t)lptr,
      16, 0, 0);
}

// ---------------------------------------------------------------- f32 -> bf16
__global__ __launch_bounds__(256) void cast_bf16(const float* __restrict__ in,
                                                 unsigned short* __restrict__ out,
                                                 int n4) {
  int i = blockIdx.x * 256 + threadIdx.x;
  int stride = gridDim.x * 256;
  for (; i < n4; i += stride) {
    float4 v = ((const float4*)in)[i];
    ushort4 o;
    o.x = f2bf(v.x); o.y = f2bf(v.y); o.z = f2bf(v.z); o.w = f2bf(v.w);
    ((ushort4*)out)[i] = o;
  }
}

// ------------------------------------------------------- GEMM: C = A * B^T
// A [M][K] bf16 row-major, B [N][K] bf16 row-major, C [M][N] f32.
// 128x128 tile, BK=32, 4 waves (2x2), 4x4 16x16x32 fragments per wave.
__global__ __launch_bounds__(256) void gemm_bt(const unsigned short* __restrict__ A,
                                               const unsigned short* __restrict__ B,
                                               float* __restrict__ C,
                                               int M, int N, int K) {
  __shared__ unsigned short As[128 * 32];
  __shared__ unsigned short Bs[128 * 32];
  const int tid  = threadIdx.x;
  const int lane = tid & 63;
  const int w    = tid >> 6;
  const int wr   = (w >> 1) * 64;
  const int wc   = (w & 1) * 64;
  const int bm   = blockIdx.y * 128;
  const int bn   = blockIdx.x * 128;
  const int l15  = lane & 15;
  const int lg   = lane >> 4;

  f32x4 acc[4][4] = {};

  for (int kt = 0; kt < K; kt += 32) {
#pragma unroll
    for (int p = 0; p < 2; ++p) {
      const int c = p * 256 + tid;            // chunk id 0..511, == base+lane
      gload_lds16(A + (size_t)(bm + (c >> 2)) * K + kt + (c & 3) * 8,
                  &As[(p * 256 + w * 64) * 8]);
      gload_lds16(B + (size_t)(bn + (c >> 2)) * K + kt + (c & 3) * 8,
                  &Bs[(p * 256 + w * 64) * 8]);
    }
    __syncthreads();
    bf16x8 af[4], bfb[4];
#pragma unroll
    for (int m = 0; m < 4; ++m)
      af[m] = *(const bf16x8*)&As[(wr + m * 16 + l15) * 32 + lg * 8];
#pragma unroll
    for (int n = 0; n < 4; ++n)
      bfb[n] = *(const bf16x8*)&Bs[(wc + n * 16 + l15) * 32 + lg * 8];
#pragma unroll
    for (int m = 0; m < 4; ++m)
#pragma unroll
      for (int n = 0; n < 4; ++n)
        acc[m][n] = __builtin_amdgcn_mfma_f32_16x16x32_bf16(af[m], bfb[n], acc[m][n], 0, 0, 0);
    __syncthreads();
  }

  // C/D layout: col = lane&15, row = (lane>>4)*4 + i
#pragma unroll
  for (int m = 0; m < 4; ++m)
#pragma unroll
    for (int i = 0; i < 4; ++i) {
      const int row = bm + wr + m * 16 + lg * 4 + i;
#pragma unroll
      for (int n = 0; n < 4; ++n)
        C[(size_t)row * N + bn + wc + n * 16 + l15] = acc[m][n][i];
    }
}

// ---------------------------------------- LayerNorm + RoPE + split/cast kernel
// qkv f32 [T][12288] -> q bf16 [T][4096] (scaled by QSCALE), k bf16, v bf16
__global__ __launch_bounds__(256) void norm_rope(const float* __restrict__ qkv,
                                                 const float* __restrict__ qw,
                                                 const float* __restrict__ qb,
                                                 const float* __restrict__ kw,
                                                 const float* __restrict__ kb,
                                                 unsigned short* __restrict__ q,
                                                 unsigned short* __restrict__ k,
                                                 unsigned short* __restrict__ v) {
  const int t    = blockIdx.x;
  const int tid  = threadIdx.x;
  const int lane = tid & 63;
  const int w    = tid >> 6;
  // positions[t] == t by construction (arange)
  const float invf = exp2f(-(float)lane * (13.287712379549449f / 64.0f)); // 10000^(-lane/64)
  const float ang  = (float)t * invf;
  const float c = cosf(ang), s = sinf(ang);
  const float* row = qkv + (size_t)t * QKVW;

#pragma unroll 1
  for (int sel = 0; sel < 2; ++sel) {
    const float* src = row + sel * HID;
    const float* wgt = sel ? kw : qw;
    const float* bia = sel ? kb : qb;
    unsigned short* dst = sel ? k : q;
    const float oscale = sel ? 1.0f : QSCALE;
    for (int h = w; h < NH; h += 4) {
      const float* x = src + h * HD;
      float x1 = x[lane], x2 = x[lane + 64];
      float sum = x1 + x2, ss = x1 * x1 + x2 * x2;
#pragma unroll
      for (int m = 1; m < 64; m <<= 1) {
        sum += __shfl_xor(sum, m, 64);
        ss  += __shfl_xor(ss, m, 64);
      }
      const float mu  = sum * (1.0f / 128.0f);
      const float var = ss * (1.0f / 128.0f) - mu * mu;
      const float r   = rsqrtf(var + 1e-5f);
      const float n1  = (x1 - mu) * r * wgt[h * HD + lane]      + bia[h * HD + lane];
      const float n2  = (x2 - mu) * r * wgt[h * HD + lane + 64] + bia[h * HD + lane + 64];
      const float o1  = (n1 * c - n2 * s) * oscale;
      const float o2  = (n2 * c + n1 * s) * oscale;
      dst[(size_t)t * HID + h * HD + lane]      = f2bf(o1);
      dst[(size_t)t * HID + h * HD + lane + 64] = f2bf(o2);
    }
  }
  // v: plain cast
  const float* vx = row + 2 * HID;
  unsigned short* vdst = v + (size_t)t * HID;
  for (int j = tid; j < HID / 4; j += 256) {
    float4 val = ((const float4*)vx)[j];
    ushort4 o;
    o.x = f2bf(val.x); o.y = f2bf(val.y); o.z = f2bf(val.z); o.w = f2bf(val.w);
    ((ushort4*)vdst)[j] = o;
  }
}

// ------------------------------------------- V transpose: [T][H][D]->[H][D][T]
__global__ __launch_bounds__(256) void transpose_v(const unsigned short* __restrict__ v,
                                                   unsigned short* __restrict__ vt) {
  __shared__ unsigned short tile[64][65];
  const int h  = blockIdx.z;
  const int tt = blockIdx.x * 64;
  const int dd = blockIdx.y * 64;
  const int tid = threadIdx.x;
#pragma unroll
  for (int p = 0; p < 4; ++p) {
    int idx = p * 256 + tid;
    int r = idx >> 4, c4 = idx & 15;
    ushort4 val = *(const ushort4*)&v[(size_t)(tt + r) * HID + h * HD + dd + c4 * 4];
    tile[r][c4 * 4 + 0] = val.x;
    tile[r][c4 * 4 + 1] = val.y;
    tile[r][c4 * 4 + 2] = val.z;
    tile[r][c4 * 4 + 3] = val.w;
  }
  __syncthreads();
#pragma unroll
  for (int p = 0; p < 4; ++p) {
    int idx = p * 256 + tid;
    int r = idx >> 4, c4 = idx & 15;   // r: d-local row, c4: t-local col/4
    ushort4 o;
    o.x = tile[c4 * 4 + 0][r];
    o.y = tile[c4 * 4 + 1][r];
    o.z = tile[c4 * 4 + 2][r];
    o.w = tile[c4 * 4 + 3][r];
    *(ushort4*)&vt[((size_t)h * HD + dd + r) * T_SEQ + tt + c4 * 4] = o;
  }
}

// -------------------------------------------------- causal flash attention
// Q [T][H*D] bf16 (pre-scaled, log2 domain), K [T][H*D] bf16, VT [H][D][T] bf16
// out [T][H*D] bf16. Block: 4 waves, 64 q-rows (16 per wave), KV tile 32.
__global__ __launch_bounds__(256) void attn_fwd(const unsigned short* __restrict__ Q,
                                                const unsigned short* __restrict__ K,
                                                const unsigned short* __restrict__ VT,
                                                unsigned short* __restrict__ O) {
  __shared__ unsigned short Ks[32 * 128];   // [kv][d]
  __shared__ unsigned short Vs[128 * 32];   // [d][kv]
  __shared__ unsigned short Ps[4][16 * 32]; // per-wave P [qrow][kv]
  const int h   = blockIdx.y;
  const int qt  = blockIdx.x;
  const int q0  = qt * 64;
  const int tid = threadIdx.x;
  const int lane = tid & 63;
  const int w    = tid >> 6;
  const int l15  = lane & 15;
  const int lg   = lane >> 4;
  const int qrow = q0 + w * 16;

  bf16x8 qf[4];
#pragma unroll
  for (int ks = 0; ks < 4; ++ks)
    qf[ks] = *(const bf16x8*)&Q[(size_t)(qrow + l15) * HID + h * HD + ks * 32 + lg * 8];

  f32x4 o[8] = {};
  float mrow[4], lrow[4];
#pragma unroll
  for (int i = 0; i < 4; ++i) { mrow[i] = -1e30f; lrow[i] = 0.0f; }

  const int nkt = 2 * qt + 2;
  for (int kt = 0; kt < nkt; ++kt) {
    __syncthreads();  // previous iter's LDS reads done
#pragma unroll
    for (int p = 0; p < 2; ++p) {
      const int c = p * 256 + tid;
      gload_lds16(&K[(size_t)(kt * 32 + (c >> 4)) * HID + h * HD + (c & 15) * 8],
                  &Ks[(p * 256 + w * 64) * 8]);
      gload_lds16(&VT[((size_t)h * HD + (c >> 2)) * T_SEQ + kt * 32 + (c & 3) * 8],
                  &Vs[(p * 256 + w * 64) * 8]);
    }
    __syncthreads();  // K,V staged

    f32x4 sfr[2] = {};
#pragma unroll
    for (int n = 0; n < 2; ++n)
#pragma unroll
      for (int ks = 0; ks < 4; ++ks) {
        bf16x8 kf = *(const bf16x8*)&Ks[(n * 16 + l15) * 128 + ks * 32 + lg * 8];
        sfr[n] = __builtin_amdgcn_mfma_f32_16x16x32_bf16(qf[ks], kf, sfr[n], 0, 0, 0);
      }

    float escale[4], rsum[4];
#pragma unroll
    for (int i = 0; i < 4; ++i) {
      const int qa = qrow + lg * 4 + i;
#pragma unroll
      for (int n = 0; n < 2; ++n)
        if (kt * 32 + n * 16 + l15 > qa) sfr[n][i] = -1e30f;
      float mx = fmaxf(sfr[0][i], sfr[1][i]);
      mx = fmaxf(mx, __shfl_xor(mx, 1, 64));
      mx = fmaxf(mx, __shfl_xor(mx, 2, 64));
      mx = fmaxf(mx, __shfl_xor(mx, 4, 64));
      mx = fmaxf(mx, __shfl_xor(mx, 8, 64));
      const float mnew = fmaxf(mrow[i], mx);
      escale[i] = exp2f(mrow[i] - mnew);
      mrow[i] = mnew;
      const float p0 = exp2f(sfr[0][i] - mnew);
      const float p1 = exp2f(sfr[1][i] - mnew);
      rsum[i] = p0 + p1;
      Ps[w][(lg * 4 + i) * 32 + l15]      = f2bf(p0);
      Ps[w][(lg * 4 + i) * 32 + 16 + l15] = f2bf(p1);
    }
#pragma unroll
    for (int i = 0; i < 4; ++i) {
      float sg = rsum[i];
      sg += __shfl_xor(sg, 1, 64);
      sg += __shfl_xor(sg, 2, 64);
      sg += __shfl_xor(sg, 4, 64);
      sg += __shfl_xor(sg, 8, 64);
      lrow[i] = lrow[i] * escale[i] + sg;
    }
#pragma unroll
    for (int f = 0; f < 8; ++f)
#pragma unroll
      for (int i = 0; i < 4; ++i) o[f][i] *= escale[i];

    __syncthreads();  // P visible (per-wave, but uniform barrier is simplest)

    bf16x8 pf = *(const bf16x8*)&Ps[w][l15 * 32 + lg * 8];
#pragma unroll
    for (int f = 0; f < 8; ++f) {
      bf16x8 vf = *(const bf16x8*)&Vs[(f * 16 + l15) * 32 + lg * 8];
      o[f] = __builtin_amdgcn_mfma_f32_16x16x32_bf16(pf, vf, o[f], 0, 0, 0);
    }
  }

#pragma unroll
  for (int i = 0; i < 4; ++i) {
    const float inv = 1.0f / lrow[i];
    const int trow = qrow + lg * 4 + i;
#pragma unroll
    for (int f = 0; f < 8; ++f)
      O[(size_t)trow * HID + h * HD + f * 16 + l15] = f2bf(o[f][i] * inv);
  }
}

// ------------------------------------------------------------------- launch
extern "C" void kernel_launch(void* const* d_in, const int* in_sizes, int n_in,
                              void* d_out, int out_size, void* d_ws, size_t ws_size,
                              hipStream_t stream) {
  const float* hidden = (const float*)d_in[1];
  const float* w_qkv  = (const float*)d_in[2];
  const float* w_o    = (const float*)d_in[3];
  const float* qw     = (const float*)d_in[4];
  const float* qb     = (const float*)d_in[5];
  const float* kw     = (const float*)d_in[6];
  const float* kb     = (const float*)d_in[7];

  char* ws = (char*)d_ws;
  // region A (100663296 B): w_qkv_bf16 during GEMM1; then attn_bf16 + w_o_bf16
  unsigned short* wqkv_bf = (unsigned short*)(ws + 0);
  unsigned short* attn_bf = (unsigned short*)(ws + 0);
  unsigned short* wo_bf   = (unsigned short*)(ws + 16777216);
  // region B (16777216 B): hidden_bf16 during GEMM1; then vt
  unsigned short* hid_bf  = (unsigned short*)(ws + 100663296);
  unsigned short* vt_bf   = (unsigned short*)(ws + 100663296);
  // region C: qkv f32
  float* qkv_f32          = (float*)(ws + 117440512);
  // region D: q,k,v bf16
  unsigned short* q_bf    = (unsigned short*)(ws + 218103808);
  unsigned short* k_bf    = (unsigned short*)(ws + 234881024);
  unsigned short* v_bf    = (unsigned short*)(ws + 251658240);

  cast_bf16<<<2048, 256, 0, stream>>>(hidden, hid_bf, (T_SEQ * HID) / 4);
  cast_bf16<<<2048, 256, 0, stream>>>(w_qkv, wqkv_bf, (QKVW * HID) / 4);
  gemm_bt<<<dim3(QKVW / 128, T_SEQ / 128), 256, 0, stream>>>(
      hid_bf, wqkv_bf, qkv_f32, T_SEQ, QKVW, HID);
  cast_bf16<<<2048, 256, 0, stream>>>(w_o, wo_bf, (HID * HID) / 4);
  norm_rope<<<T_SEQ, 256, 0, stream>>>(qkv_f32, qw, qb, kw, kb, q_bf, k_bf, v_bf);
  transpose_v<<<dim3(T_SEQ / 64, HD / 64, NH), 256, 0, stream>>>(v_bf, vt_bf);
  attn_fwd<<<dim3(T_SEQ / 64, NH), 256, 0, stream>>>(q_bf, k_bf, vt_bf, attn_bf);
  gemm_bt<<<dim3(HID / 128, T_SEQ / 128), 256, 0, stream>>>(
      attn_bf, wo_bf, (float*)d_out, T_SEQ, HID, HID);
}

// Round 2
// 615.508 us; speedup vs baseline: 1.3213x; 1.3213x over previous
//
#include <hip/hip_runtime.h>
#include <cstdint>

#define T_SEQ 2048
#define HID   4096
#define NH    32
#define HD    128
#define QKVW  12288   // (32 + 2*32) * 128

typedef float  f32x4  __attribute__((ext_vector_type(4)));
typedef __bf16 bf16x8 __attribute__((ext_vector_type(8)));

// log2(e)/sqrt(128): fold softmax scale + base-2 conversion into Q
#define QSCALE (0.08838834764831845f * 1.4426950408889634f)

__device__ __forceinline__ unsigned short f2bf(float f) {
  unsigned int u = __builtin_bit_cast(unsigned int, f);
  u += 0x7fffu + ((u >> 16) & 1u);          // round-to-nearest-even (inputs finite)
  return (unsigned short)(u >> 16);
}

// async global->LDS, 16B per lane. LDS dest is wave-uniform base + lane*16.
__device__ __forceinline__ void gload_lds16(const void* gptr, void* lptr) {
  __builtin_amdgcn_global_load_lds(
      (const __attribute__((address_space(1))) unsigned int*)(unsigned long long)(uintptr_t)gptr,
      (__attribute__((address_space(3))) unsigned int*)(unsigned int)(uintptr_t)lptr,
      16, 0, 0);
}

// ---------------------------------------------------------------- f32 -> bf16
__global__ __launch_bounds__(256) void cast_bf16(const float* __restrict__ in,
                                                 unsigned short* __restrict__ out,
                                                 int n4) {
  int i = blockIdx.x * 256 + threadIdx.x;
  int stride = gridDim.x * 256;
  for (; i < n4; i += stride) {
    float4 v = ((const float4*)in)[i];
    ushort4 o;
    o.x = f2bf(v.x); o.y = f2bf(v.y); o.z = f2bf(v.z); o.w = f2bf(v.w);
    ((ushort4*)out)[i] = o;
  }
}

// ------------------------------------------------------- GEMM: C = A * B^T
// A [M][K] bf16 row-major, B [N][K] bf16 row-major, C [M][N] f32.
// 128x128 tile, BK=32, 4 waves (2x2), 4x4 16x16x32 fragments per wave.
__global__ __launch_bounds__(256) void gemm_bt(const unsigned short* __restrict__ A,
                                               const unsigned short* __restrict__ B,
                                               float* __restrict__ C,
                                               int M, int N, int K) {
  __shared__ unsigned short As[128 * 32];
  __shared__ unsigned short Bs[128 * 32];
  const int tid  = threadIdx.x;
  const int lane = tid & 63;
  const int w    = tid >> 6;
  const int wr   = (w >> 1) * 64;
  const int wc   = (w & 1) * 64;
  const int bm   = blockIdx.y * 128;
  const int bn   = blockIdx.x * 128;
  const int l15  = lane & 15;
  const int lg   = lane >> 4;

  f32x4 acc[4][4] = {};

  for (int kt = 0; kt < K; kt += 32) {
#pragma unroll
    for (int p = 0; p < 2; ++p) {
      const int c = p * 256 + tid;            // chunk id 0..511, == base+lane
      gload_lds16(A + (size_t)(bm + (c >> 2)) * K + kt + (c & 3) * 8,
                  &As[(p * 256 + w * 64) * 8]);
      gload_lds16(B + (size_t)(bn + (c >> 2)) * K + kt + (c & 3) * 8,
                  &Bs[(p * 256 + w * 64) * 8]);
    }
    __syncthreads();
    bf16x8 af[4], bfb[4];
#pragma unroll
    for (int m = 0; m < 4; ++m)
      af[m] = *(const bf16x8*)&As[(wr + m * 16 + l15) * 32 + lg * 8];
#pragma unroll
    for (int n = 0; n < 4; ++n)
      bfb[n] = *(const bf16x8*)&Bs[(wc + n * 16 + l15) * 32 + lg * 8];
#pragma unroll
    for (int m = 0; m < 4; ++m)
#pragma unroll
      for (int n = 0; n < 4; ++n)
        acc[m][n] = __builtin_amdgcn_mfma_f32_16x16x32_bf16(af[m], bfb[n], acc[m][n], 0, 0, 0);
    __syncthreads();
  }

  // C/D layout: col = lane&15, row = (lane>>4)*4 + i
#pragma unroll
  for (int m = 0; m < 4; ++m)
#pragma unroll
    for (int i = 0; i < 4; ++i) {
      const int row = bm + wr + m * 16 + lg * 4 + i;
#pragma unroll
      for (int n = 0; n < 4; ++n)
        C[(size_t)row * N + bn + wc + n * 16 + l15] = acc[m][n][i];
    }
}

// ---------------------------------------- LayerNorm + RoPE + split/cast kernel
// qkv f32 [T][12288] -> q bf16 [T][4096] (scaled by QSCALE), k bf16, v bf16
__global__ __launch_bounds__(256) void norm_rope(const float* __restrict__ qkv,
                                                 const float* __restrict__ qw,
                                                 const float* __restrict__ qb,
                                                 const float* __restrict__ kw,
                                                 const float* __restrict__ kb,
                                                 unsigned short* __restrict__ q,
                                                 unsigned short* __restrict__ k,
                                                 unsigned short* __restrict__ v) {
  const int t    = blockIdx.x;
  const int tid  = threadIdx.x;
  const int lane = tid & 63;
  const int w    = tid >> 6;
  // positions[t] == t by construction (arange)
  const float invf = exp2f(-(float)lane * (13.287712379549449f / 64.0f)); // 10000^(-lane/64)
  const float ang  = (float)t * invf;
  const float c = cosf(ang), s = sinf(ang);
  const float* row = qkv + (size_t)t * QKVW;

#pragma unroll 1
  for (int sel = 0; sel < 2; ++sel) {
    const float* src = row + sel * HID;
    const float* wgt = sel ? kw : qw;
    const float* bia = sel ? kb : qb;
    unsigned short* dst = sel ? k : q;
    const float oscale = sel ? 1.0f : QSCALE;
    for (int h = w; h < NH; h += 4) {
      const float* x = src + h * HD;
      float x1 = x[lane], x2 = x[lane + 64];
      float sum = x1 + x2, ss = x1 * x1 + x2 * x2;
#pragma unroll
      for (int m = 1; m < 64; m <<= 1) {
        sum += __shfl_xor(sum, m, 64);
        ss  += __shfl_xor(ss, m, 64);
      }
      const float mu  = sum * (1.0f / 128.0f);
      const float var = ss * (1.0f / 128.0f) - mu * mu;
      const float r   = rsqrtf(var + 1e-5f);
      const float n1  = (x1 - mu) * r * wgt[h * HD + lane]      + bia[h * HD + lane];
      const float n2  = (x2 - mu) * r * wgt[h * HD + lane + 64] + bia[h * HD + lane + 64];
      const float o1  = (n1 * c - n2 * s) * oscale;
      const float o2  = (n2 * c + n1 * s) * oscale;
      dst[(size_t)t * HID + h * HD + lane]      = f2bf(o1);
      dst[(size_t)t * HID + h * HD + lane + 64] = f2bf(o2);
    }
  }
  // v: plain cast
  const float* vx = row + 2 * HID;
  unsigned short* vdst = v + (size_t)t * HID;
  for (int j = tid; j < HID / 4; j += 256) {
    float4 val = ((const float4*)vx)[j];
    ushort4 o;
    o.x = f2bf(val.x); o.y = f2bf(val.y); o.z = f2bf(val.z); o.w = f2bf(val.w);
    ((ushort4*)vdst)[j] = o;
  }
}

// ------------------------------------------- V transpose: [T][H][D]->[H][D][T]
__global__ __launch_bounds__(256) void transpose_v(const unsigned short* __restrict__ v,
                                                   unsigned short* __restrict__ vt) {
  __shared__ unsigned short tile[64][65];
  const int h  = blockIdx.z;
  const int tt = blockIdx.x * 64;
  const int dd = blockIdx.y * 64;
  const int tid = threadIdx.x;
#pragma unroll
  for (int p = 0; p < 4; ++p) {
    int idx = p * 256 + tid;
    int r = idx >> 4, c4 = idx & 15;
    ushort4 val = *(const ushort4*)&v[(size_t)(tt + r) * HID + h * HD + dd + c4 * 4];
    tile[r][c4 * 4 + 0] = val.x;
    tile[r][c4 * 4 + 1] = val.y;
    tile[r][c4 * 4 + 2] = val.z;
    tile[r][c4 * 4 + 3] = val.w;
  }
  __syncthreads();
#pragma unroll
  for (int p = 0; p < 4; ++p) {
    int idx = p * 256 + tid;
    int r = idx >> 4, c4 = idx & 15;   // r: d-local row, c4: t-local col/4
    ushort4 o;
    o.x = tile[c4 * 4 + 0][r];
    o.y = tile[c4 * 4 + 1][r];
    o.z = tile[c4 * 4 + 2][r];
    o.w = tile[c4 * 4 + 3][r];
    *(ushort4*)&vt[((size_t)h * HD + dd + r) * T_SEQ + tt + c4 * 4] = o;
  }
}

// -------------------------------------------------- causal flash attention
// Q [T][H*D] bf16 (pre-scaled, log2 domain), K [T][H*D] bf16, VT [H][D][T] bf16
// out [T][H*D] bf16.
// Block: 4 waves = 64 q-rows (16/wave). KVBLK=64, double-buffered LDS,
// XOR-swizzled (chunk ^= row&7, 16B chunks) K/V/P tiles, q-tile pairing
// (b, 31-b) for uniform causal work (33 kv-iters per block).
__global__ __launch_bounds__(256) void attn_fwd(const unsigned short* __restrict__ Q,
                                                const unsigned short* __restrict__ K,
                                                const unsigned short* __restrict__ VT,
                                                unsigned short* __restrict__ O) {
  __shared__ unsigned short Ks[2][64 * 128];  // [kv][d], swizzled
  __shared__ unsigned short Vs[2][128 * 64];  // [d][kv], swizzled
  __shared__ unsigned short Ps[4][16 * 64];   // per-wave [qrow][kv], swizzled
  const int h    = blockIdx.y;
  const int pair = blockIdx.x;                 // 0..15
  const int tid  = threadIdx.x;
  const int lane = tid & 63;
  const int w    = tid >> 6;
  const int l15  = lane & 15;
  const int lg   = lane >> 4;
  const int sw   = l15 & 7;

#pragma unroll 1
  for (int half = 0; half < 2; ++half) {
    const int qt   = half ? (31 - pair) : pair;   // 64-row q-tile index
    const int qrow = qt * 64 + w * 16;

    bf16x8 qf[4];
#pragma unroll
    for (int kk = 0; kk < 4; ++kk)
      qf[kk] = *(const bf16x8*)&Q[(size_t)(qrow + l15) * HID + h * HD + kk * 32 + lg * 8];

    f32x4 o[8] = {};
    float mrow[4], lrow[4];
#pragma unroll
    for (int i = 0; i < 4; ++i) { mrow[i] = -1e30f; lrow[i] = 0.0f; }

    const int nkt = qt + 1;

    // prologue: stage kv-tile 0 into buffer 0 (swizzled source, linear LDS dest)
    {
#pragma unroll
      for (int p = 0; p < 4; ++p) {
        const int c  = p * 256 + tid;
        const int kr = c >> 4, kc = c & 15;
        gload_lds16(&K[(size_t)kr * HID + h * HD + ((kc ^ (kr & 7)) * 8)],
                    &Ks[0][(p * 256 + w * 64) * 8]);
        const int vr = c >> 3, vc = c & 7;
        gload_lds16(&VT[((size_t)h * HD + vr) * T_SEQ + ((vc ^ (vr & 7)) * 8)],
                    &Vs[0][(p * 256 + w * 64) * 8]);
      }
    }
    __syncthreads();

#pragma unroll 1
    for (int kt = 0; kt < nkt; ++kt) {
      const int cur = kt & 1;
      // issue next-tile stage before compute (T3 minimum 2-phase)
      if (kt + 1 < nkt) {
        const int k0 = (kt + 1) * 64;
#pragma unroll
        for (int p = 0; p < 4; ++p) {
          const int c  = p * 256 + tid;
          const int kr = c >> 4, kc = c & 15;
          gload_lds16(&K[(size_t)(k0 + kr) * HID + h * HD + ((kc ^ (kr & 7)) * 8)],
                      &Ks[cur ^ 1][(p * 256 + w * 64) * 8]);
          const int vr = c >> 3, vc = c & 7;
          gload_lds16(&VT[((size_t)h * HD + vr) * T_SEQ + k0 + ((vc ^ (vr & 7)) * 8)],
                      &Vs[cur ^ 1][(p * 256 + w * 64) * 8]);
        }
      }
      const unsigned short* ksb = Ks[cur];
      const unsigned short* vsb = Vs[cur];

      // QK^T: S[q=16][kv=64], swizzled K reads (conflict-free)
      f32x4 sfr[4] = {};
#pragma unroll
      for (int n = 0; n < 4; ++n)
#pragma unroll
        for (int kk = 0; kk < 4; ++kk) {
          bf16x8 kf = *(const bf16x8*)&ksb[(n * 16 + l15) * 128 + ((kk * 4 + lg) ^ sw) * 8];
          sfr[n] = __builtin_amdgcn_mfma_f32_16x16x32_bf16(qf[kk], kf, sfr[n], 0, 0, 0);
        }

      if (kt == qt) {  // diagonal tile: causal mask (within-tile coords)
#pragma unroll
        for (int n = 0; n < 4; ++n)
#pragma unroll
          for (int i = 0; i < 4; ++i)
            if (n * 16 + l15 > w * 16 + lg * 4 + i) sfr[n][i] = -1e30f;
      }

      // online softmax (base-2 domain; scale folded into Q)
      float escale[4];
#pragma unroll
      for (int i = 0; i < 4; ++i) {
        float mx = fmaxf(fmaxf(sfr[0][i], sfr[1][i]), fmaxf(sfr[2][i], sfr[3][i]));
        mx = fmaxf(mx, __shfl_xor(mx, 1, 64));
        mx = fmaxf(mx, __shfl_xor(mx, 2, 64));
        mx = fmaxf(mx, __shfl_xor(mx, 4, 64));
        mx = fmaxf(mx, __shfl_xor(mx, 8, 64));
        const float mnew = fmaxf(mrow[i], mx);
        escale[i] = exp2f(mrow[i] - mnew);
        mrow[i] = mnew;
        const int prow = lg * 4 + i;
        float rs = 0.0f;
#pragma unroll
        for (int n = 0; n < 4; ++n) {
          const float p = exp2f(sfr[n][i] - mnew);
          rs += p;
          Ps[w][prow * 64 + (((2 * n + (l15 >> 3)) ^ (prow & 7)) * 8) + sw] = f2bf(p);
        }
        rs += __shfl_xor(rs, 1, 64);
        rs += __shfl_xor(rs, 2, 64);
        rs += __shfl_xor(rs, 4, 64);
        rs += __shfl_xor(rs, 8, 64);
        lrow[i] = lrow[i] * escale[i] + rs;
      }
#pragma unroll
      for (int f = 0; f < 8; ++f)
#pragma unroll
        for (int i = 0; i < 4; ++i) o[f][i] *= escale[i];

      // P is wave-private: no barrier, just drain LDS writes
      asm volatile("s_waitcnt lgkmcnt(0)" ::: "memory");
      __builtin_amdgcn_sched_barrier(0);

      bf16x8 pf[2];
#pragma unroll
      for (int kk = 0; kk < 2; ++kk)
        pf[kk] = *(const bf16x8*)&Ps[w][l15 * 64 + ((kk * 4 + lg) ^ sw) * 8];
#pragma unroll
      for (int f = 0; f < 8; ++f)
#pragma unroll
        for (int kk = 0; kk < 2; ++kk) {
          bf16x8 vf = *(const bf16x8*)&vsb[(f * 16 + l15) * 64 + ((kk * 4 + lg) ^ sw) * 8];
          o[f] = __builtin_amdgcn_mfma_f32_16x16x32_bf16(pf[kk], vf, o[f], 0, 0, 0);
        }

      __syncthreads();  // reads of buf[cur] done; stage into buf[cur^1] drained
    }

#pragma unroll
    for (int i = 0; i < 4; ++i) {
      const float inv = 1.0f / lrow[i];
      const int trow = qrow + lg * 4 + i;
#pragma unroll
      for (int f = 0; f < 8; ++f)
        O[(size_t)trow * HID + h * HD + f * 16 + l15] = f2bf(o[f][i] * inv);
    }
  }
}

// ------------------------------------------------------------------- launch
extern "C" void kernel_launch(void* const* d_in, const int* in_sizes, int n_in,
                              void* d_out, int out_size, void* d_ws, size_t ws_size,
                              hipStream_t stream) {
  const float* hidden = (const float*)d_in[1];
  const float* w_qkv  = (const float*)d_in[2];
  const float* w_o    = (const float*)d_in[3];
  const float* qw     = (const float*)d_in[4];
  const float* qb     = (const float*)d_in[5];
  const float* kw     = (const float*)d_in[6];
  const float* kb     = (const float*)d_in[7];

  char* ws = (char*)d_ws;
  // region A (100663296 B): w_qkv_bf16 during GEMM1; then attn_bf16 + w_o_bf16
  unsigned short* wqkv_bf = (unsigned short*)(ws + 0);
  unsigned short* attn_bf = (unsigned short*)(ws + 0);
  unsigned short* wo_bf   = (unsigned short*)(ws + 16777216);
  // region B (16777216 B): hidden_bf16 during GEMM1; then vt
  unsigned short* hid_bf  = (unsigned short*)(ws + 100663296);
  unsigned short* vt_bf   = (unsigned short*)(ws + 100663296);
  // region C: qkv f32
  float* qkv_f32          = (float*)(ws + 117440512);
  // region D: q,k,v bf16
  unsigned short* q_bf    = (unsigned short*)(ws + 218103808);
  unsigned short* k_bf    = (unsigned short*)(ws + 234881024);
  unsigned short* v_bf    = (unsigned short*)(ws + 251658240);

  cast_bf16<<<2048, 256, 0, stream>>>(hidden, hid_bf, (T_SEQ * HID) / 4);
  cast_bf16<<<2048, 256, 0, stream>>>(w_qkv, wqkv_bf, (QKVW * HID) / 4);
  gemm_bt<<<dim3(QKVW / 128, T_SEQ / 128), 256, 0, stream>>>(
      hid_bf, wqkv_bf, qkv_f32, T_SEQ, QKVW, HID);
  cast_bf16<<<2048, 256, 0, stream>>>(w_o, wo_bf, (HID * HID) / 4);
  norm_rope<<<T_SEQ, 256, 0, stream>>>(qkv_f32, qw, qb, kw, kb, q_bf, k_bf, v_bf);
  transpose_v<<<dim3(T_SEQ / 64, HD / 64, NH), 256, 0, stream>>>(v_bf, vt_bf);
  attn_fwd<<<dim3(16, NH), 256, 0, stream>>>(q_bf, k_bf, vt_bf, attn_bf);
  gemm_bt<<<dim3(HID / 128, T_SEQ / 128), 256, 0, stream>>>(
      attn_bf, wo_bf, (float*)d_out, T_SEQ, HID, HID);
}

// Round 3
// 509.186 us; speedup vs baseline: 1.5972x; 1.2088x over previous
//
#include <hip/hip_runtime.h>
#include <cstdint>

#define T_SEQ 2048
#define HID   4096
#define NH    32
#define HD    128
#define QKVW  12288   // (32 + 2*32) * 128

typedef float  f32x4  __attribute__((ext_vector_type(4)));
typedef __bf16 bf16x8 __attribute__((ext_vector_type(8)));

// log2(e)/sqrt(128): fold softmax scale + base-2 conversion into Q
#define QSCALE (0.08838834764831845f * 1.4426950408889634f)

__device__ __forceinline__ unsigned short f2bf(float f) {
  unsigned int u = __builtin_bit_cast(unsigned int, f);
  u += 0x7fffu + ((u >> 16) & 1u);          // round-to-nearest-even (inputs finite)
  return (unsigned short)(u >> 16);
}

// async global->LDS, 16B per lane. LDS dest is wave-uniform base + lane*16.
__device__ __forceinline__ void gload_lds16(const void* gptr, void* lptr) {
  __builtin_amdgcn_global_load_lds(
      (const __attribute__((address_space(1))) unsigned int*)(unsigned long long)(uintptr_t)gptr,
      (__attribute__((address_space(3))) unsigned int*)(unsigned int)(uintptr_t)lptr,
      16, 0, 0);
}

// ---------------------------------------------------------------- f32 -> bf16
__global__ __launch_bounds__(256) void cast_bf16(const float* __restrict__ in,
                                                 unsigned short* __restrict__ out,
                                                 int n4) {
  int i = blockIdx.x * 256 + threadIdx.x;
  int stride = gridDim.x * 256;
  for (; i < n4; i += stride) {
    float4 v = ((const float4*)in)[i];
    ushort4 o;
    o.x = f2bf(v.x); o.y = f2bf(v.y); o.z = f2bf(v.z); o.w = f2bf(v.w);
    ((ushort4*)out)[i] = o;
  }
}

// ------------------------------------------------- pipelined GEMM: C = A * B^T
// A [M][K] bf16, B [N][K] bf16 (both row-major), C [M][N] f32.
// BM=128, BN=256, BK=64. 512 threads = 8 waves (2M x 4N), 64x64 per wave.
// 2 phases per K-tile (16 MFMA each), counted vmcnt(4) at tile boundary
// (never 0 in steady state), raw s_barrier (no implicit vmcnt(0) drain),
// T2 XOR-swizzled LDS (chunk ^= row&7), T5 setprio around MFMA clusters,
// T1 bijective XCD swizzle (grid % 8 == 0 for all launches here).
//
// Stage schedule (region-free windows):
//   tile t P0: issue A(t+1) (2 loads)  [A(buf^1) free since t-1 P1 barrier]
//   tile t P1: issue B(t+2) (4 loads)  [B(buf) free after t P0 reads]
//   end of t : vmcnt(4) -> A(t+1),B(t+1) complete; B(t+2) still in flight.
__global__ __launch_bounds__(512, 2) void gemm_bt(const unsigned short* __restrict__ Ag,
                                                  const unsigned short* __restrict__ Bg,
                                                  float* __restrict__ C,
                                                  int M, int N, int K, int MT) {
  __shared__ unsigned short As_[2][128 * 64];
  __shared__ unsigned short Bs_[2][256 * 64];
  const int tid  = threadIdx.x;
  const int lane = tid & 63;
  const int w    = tid >> 6;
  const int wm   = w >> 2;        // 0..1
  const int wn   = w & 3;         // 0..3
  const int l15  = lane & 15;
  const int lg   = lane >> 4;

  // XCD-aware bijective swizzle (nwg divisible by 8), m-fastest decompose:
  // concurrent blocks on one XCD share B panels (2MB, L2-resident).
  const int nwg = gridDim.x;
  const int cpx = nwg >> 3;
  const int swz = (blockIdx.x & 7) * cpx + (blockIdx.x >> 3);
  const int bm  = (swz % MT) * 128;
  const int bn  = (swz / MT) * 256;
  const int nk  = K >> 6;

#define STAGE_A(buf, kt_) do {                                                   \
    const unsigned short* _s = Ag + (size_t)bm * K + (size_t)(kt_) * 64;         \
    _Pragma("unroll")                                                            \
    for (int _u = 0; _u < 2; ++_u) {                                             \
      const int _cid = _u * 512 + tid;                                           \
      const int _r = _cid >> 3, _ch = _cid & 7;                                  \
      gload_lds16(_s + (size_t)_r * K + ((_ch ^ (_r & 7)) * 8),                  \
                  &As_[buf][(_u * 512 + w * 64) * 8]);                           \
    } } while (0)

#define STAGE_B(buf, kt_) do {                                                   \
    const unsigned short* _s = Bg + (size_t)bn * K + (size_t)(kt_) * 64;         \
    _Pragma("unroll")                                                            \
    for (int _u = 0; _u < 4; ++_u) {                                             \
      const int _cid = _u * 512 + tid;                                           \
      const int _r = _cid >> 3, _ch = _cid & 7;                                  \
      gload_lds16(_s + (size_t)_r * K + ((_ch ^ (_r & 7)) * 8),                  \
                  &Bs_[buf][(_u * 512 + w * 64) * 8]);                           \
    } } while (0)

  f32x4 acc[4][4] = {};

  // prologue: A(0), B(0) needed now; B(1) prefetched (stays in flight)
  STAGE_A(0, 0);
  STAGE_B(0, 0);
  if (nk > 1) {
    STAGE_B(1, 1);
    asm volatile("s_waitcnt vmcnt(4)" ::: "memory");
  } else {
    asm volatile("s_waitcnt vmcnt(0)" ::: "memory");
  }
  __builtin_amdgcn_s_barrier();

  for (int t = 0; t < nk; ++t) {
    const int cur = t & 1;
    // ---------------- phase 0: B frags (all) + A quadrant 0
    bf16x8 bfr[4][2];
#pragma unroll
    for (int n = 0; n < 4; ++n)
#pragma unroll
      for (int kk = 0; kk < 2; ++kk) {
        const int r = wn * 64 + n * 16 + l15;
        bfr[n][kk] = *(const bf16x8*)&Bs_[cur][r * 64 + (((kk * 4 + lg) ^ (r & 7)) * 8)];
      }
    bf16x8 a0[2][2];
#pragma unroll
    for (int mi = 0; mi < 2; ++mi)
#pragma unroll
      for (int kk = 0; kk < 2; ++kk) {
        const int r = wm * 64 + mi * 16 + l15;
        a0[mi][kk] = *(const bf16x8*)&As_[cur][r * 64 + (((kk * 4 + lg) ^ (r & 7)) * 8)];
      }
    if (t + 1 < nk) STAGE_A(cur ^ 1, t + 1);
    __builtin_amdgcn_s_barrier();
    __builtin_amdgcn_s_setprio(1);
#pragma unroll
    for (int mi = 0; mi < 2; ++mi)
#pragma unroll
      for (int n = 0; n < 4; ++n)
#pragma unroll
        for (int kk = 0; kk < 2; ++kk)
          acc[mi][n] = __builtin_amdgcn_mfma_f32_16x16x32_bf16(a0[mi][kk], bfr[n][kk], acc[mi][n], 0, 0, 0);
    __builtin_amdgcn_s_setprio(0);
    __builtin_amdgcn_s_barrier();

    // ---------------- phase 1: A quadrant 1
    bf16x8 a1[2][2];
#pragma unroll
    for (int mi = 0; mi < 2; ++mi)
#pragma unroll
      for (int kk = 0; kk < 2; ++kk) {
        const int r = wm * 64 + (2 + mi) * 16 + l15;
        a1[mi][kk] = *(const bf16x8*)&As_[cur][r * 64 + (((kk * 4 + lg) ^ (r & 7)) * 8)];
      }
    if (t + 2 < nk) STAGE_B(cur, t + 2);
    __builtin_amdgcn_s_barrier();
    __builtin_amdgcn_s_setprio(1);
#pragma unroll
    for (int mi = 0; mi < 2; ++mi)
#pragma unroll
      for (int n = 0; n < 4; ++n)
#pragma unroll
        for (int kk = 0; kk < 2; ++kk)
          acc[2 + mi][n] = __builtin_amdgcn_mfma_f32_16x16x32_bf16(a1[mi][kk], bfr[n][kk], acc[2 + mi][n], 0, 0, 0);
    __builtin_amdgcn_s_setprio(0);
    if (t + 1 < nk) {
      if (t + 2 < nk) asm volatile("s_waitcnt vmcnt(4)" ::: "memory");
      else            asm volatile("s_waitcnt vmcnt(0)" ::: "memory");
      __builtin_amdgcn_sched_barrier(0);
    }
    __builtin_amdgcn_s_barrier();
  }
#undef STAGE_A
#undef STAGE_B

  // epilogue: C/D layout col = lane&15, row = (lane>>4)*4 + i
#pragma unroll
  for (int m = 0; m < 4; ++m)
#pragma unroll
    for (int i = 0; i < 4; ++i) {
      const int row = bm + wm * 64 + m * 16 + lg * 4 + i;
#pragma unroll
      for (int n = 0; n < 4; ++n)
        C[(size_t)row * N + bn + wn * 64 + n * 16 + l15] = acc[m][n][i];
    }
}

// ---------------------------------------- LayerNorm + RoPE + split/cast kernel
// qkv f32 [T][12288] -> q bf16 [T][4096] (scaled by QSCALE), k bf16, v bf16
__global__ __launch_bounds__(256) void norm_rope(const float* __restrict__ qkv,
                                                 const float* __restrict__ qw,
                                                 const float* __restrict__ qb,
                                                 const float* __restrict__ kw,
                                                 const float* __restrict__ kb,
                                                 unsigned short* __restrict__ q,
                                                 unsigned short* __restrict__ k,
                                                 unsigned short* __restrict__ v) {
  const int t    = blockIdx.x;
  const int tid  = threadIdx.x;
  const int lane = tid & 63;
  const int w    = tid >> 6;
  // positions[t] == t by construction (arange)
  const float invf = exp2f(-(float)lane * (13.287712379549449f / 64.0f)); // 10000^(-lane/64)
  const float ang  = (float)t * invf;
  const float c = cosf(ang), s = sinf(ang);
  const float* row = qkv + (size_t)t * QKVW;

#pragma unroll 1
  for (int sel = 0; sel < 2; ++sel) {
    const float* src = row + sel * HID;
    const float* wgt = sel ? kw : qw;
    const float* bia = sel ? kb : qb;
    unsigned short* dst = sel ? k : q;
    const float oscale = sel ? 1.0f : QSCALE;
    for (int h = w; h < NH; h += 4) {
      const float* x = src + h * HD;
      float x1 = x[lane], x2 = x[lane + 64];
      float sum = x1 + x2, ss = x1 * x1 + x2 * x2;
#pragma unroll
      for (int m = 1; m < 64; m <<= 1) {
        sum += __shfl_xor(sum, m, 64);
        ss  += __shfl_xor(ss, m, 64);
      }
      const float mu  = sum * (1.0f / 128.0f);
      const float var = ss * (1.0f / 128.0f) - mu * mu;
      const float r   = rsqrtf(var + 1e-5f);
      const float n1  = (x1 - mu) * r * wgt[h * HD + lane]      + bia[h * HD + lane];
      const float n2  = (x2 - mu) * r * wgt[h * HD + lane + 64] + bia[h * HD + lane + 64];
      const float o1  = (n1 * c - n2 * s) * oscale;
      const float o2  = (n2 * c + n1 * s) * oscale;
      dst[(size_t)t * HID + h * HD + lane]      = f2bf(o1);
      dst[(size_t)t * HID + h * HD + lane + 64] = f2bf(o2);
    }
  }
  // v: plain cast
  const float* vx = row + 2 * HID;
  unsigned short* vdst = v + (size_t)t * HID;
  for (int j = tid; j < HID / 4; j += 256) {
    float4 val = ((const float4*)vx)[j];
    ushort4 o;
    o.x = f2bf(val.x); o.y = f2bf(val.y); o.z = f2bf(val.z); o.w = f2bf(val.w);
    ((ushort4*)vdst)[j] = o;
  }
}

// ------------------------------------------- V transpose: [T][H][D]->[H][D][T]
__global__ __launch_bounds__(256) void transpose_v(const unsigned short* __restrict__ v,
                                                   unsigned short* __restrict__ vt) {
  __shared__ unsigned short tile[64][65];
  const int h  = blockIdx.z;
  const int tt = blockIdx.x * 64;
  const int dd = blockIdx.y * 64;
  const int tid = threadIdx.x;
#pragma unroll
  for (int p = 0; p < 4; ++p) {
    int idx = p * 256 + tid;
    int r = idx >> 4, c4 = idx & 15;
    ushort4 val = *(const ushort4*)&v[(size_t)(tt + r) * HID + h * HD + dd + c4 * 4];
    tile[r][c4 * 4 + 0] = val.x;
    tile[r][c4 * 4 + 1] = val.y;
    tile[r][c4 * 4 + 2] = val.z;
    tile[r][c4 * 4 + 3] = val.w;
  }
  __syncthreads();
#pragma unroll
  for (int p = 0; p < 4; ++p) {
    int idx = p * 256 + tid;
    int r = idx >> 4, c4 = idx & 15;   // r: d-local row, c4: t-local col/4
    ushort4 o;
    o.x = tile[c4 * 4 + 0][r];
    o.y = tile[c4 * 4 + 1][r];
    o.z = tile[c4 * 4 + 2][r];
    o.w = tile[c4 * 4 + 3][r];
    *(ushort4*)&vt[((size_t)h * HD + dd + r) * T_SEQ + tt + c4 * 4] = o;
  }
}

// -------------------------------------------------- causal flash attention
// Q [T][H*D] bf16 (pre-scaled, log2 domain), K [T][H*D] bf16, VT [H][D][T] bf16
// out [T][H*D] bf16.
// Block: 4 waves = 64 q-rows (16/wave). KVBLK=64, double-buffered LDS,
// XOR-swizzled (chunk ^= row&7, 16B chunks) K/V/P tiles, q-tile pairing
// (b, 31-b) for uniform causal work (33 kv-iters per block).
__global__ __launch_bounds__(256) void attn_fwd(const unsigned short* __restrict__ Q,
                                                const unsigned short* __restrict__ K,
                                                const unsigned short* __restrict__ VT,
                                                unsigned short* __restrict__ O) {
  __shared__ unsigned short Ks[2][64 * 128];  // [kv][d], swizzled
  __shared__ unsigned short Vs[2][128 * 64];  // [d][kv], swizzled
  __shared__ unsigned short Ps[4][16 * 64];   // per-wave [qrow][kv], swizzled
  const int h    = blockIdx.y;
  const int pair = blockIdx.x;                 // 0..15
  const int tid  = threadIdx.x;
  const int lane = tid & 63;
  const int w    = tid >> 6;
  const int l15  = lane & 15;
  const int lg   = lane >> 4;
  const int sw   = l15 & 7;

#pragma unroll 1
  for (int half = 0; half < 2; ++half) {
    const int qt   = half ? (31 - pair) : pair;   // 64-row q-tile index
    const int qrow = qt * 64 + w * 16;

    bf16x8 qf[4];
#pragma unroll
    for (int kk = 0; kk < 4; ++kk)
      qf[kk] = *(const bf16x8*)&Q[(size_t)(qrow + l15) * HID + h * HD + kk * 32 + lg * 8];

    f32x4 o[8] = {};
    float mrow[4], lrow[4];
#pragma unroll
    for (int i = 0; i < 4; ++i) { mrow[i] = -1e30f; lrow[i] = 0.0f; }

    const int nkt = qt + 1;

    // prologue: stage kv-tile 0 into buffer 0 (swizzled source, linear LDS dest)
    {
#pragma unroll
      for (int p = 0; p < 4; ++p) {
        const int c  = p * 256 + tid;
        const int kr = c >> 4, kc = c & 15;
        gload_lds16(&K[(size_t)kr * HID + h * HD + ((kc ^ (kr & 7)) * 8)],
                    &Ks[0][(p * 256 + w * 64) * 8]);
        const int vr = c >> 3, vc = c & 7;
        gload_lds16(&VT[((size_t)h * HD + vr) * T_SEQ + ((vc ^ (vr & 7)) * 8)],
                    &Vs[0][(p * 256 + w * 64) * 8]);
      }
    }
    __syncthreads();

#pragma unroll 1
    for (int kt = 0; kt < nkt; ++kt) {
      const int cur = kt & 1;
      // issue next-tile stage before compute (T3 minimum 2-phase)
      if (kt + 1 < nkt) {
        const int k0 = (kt + 1) * 64;
#pragma unroll
        for (int p = 0; p < 4; ++p) {
          const int c  = p * 256 + tid;
          const int kr = c >> 4, kc = c & 15;
          gload_lds16(&K[(size_t)(k0 + kr) * HID + h * HD + ((kc ^ (kr & 7)) * 8)],
                      &Ks[cur ^ 1][(p * 256 + w * 64) * 8]);
          const int vr = c >> 3, vc = c & 7;
          gload_lds16(&VT[((size_t)h * HD + vr) * T_SEQ + k0 + ((vc ^ (vr & 7)) * 8)],
                      &Vs[cur ^ 1][(p * 256 + w * 64) * 8]);
        }
      }
      const unsigned short* ksb = Ks[cur];
      const unsigned short* vsb = Vs[cur];

      // QK^T: S[q=16][kv=64], swizzled K reads (conflict-free)
      f32x4 sfr[4] = {};
#pragma unroll
      for (int n = 0; n < 4; ++n)
#pragma unroll
        for (int kk = 0; kk < 4; ++kk) {
          bf16x8 kf = *(const bf16x8*)&ksb[(n * 16 + l15) * 128 + ((kk * 4 + lg) ^ sw) * 8];
          sfr[n] = __builtin_amdgcn_mfma_f32_16x16x32_bf16(qf[kk], kf, sfr[n], 0, 0, 0);
        }

      if (kt == qt) {  // diagonal tile: causal mask (within-tile coords)
#pragma unroll
        for (int n = 0; n < 4; ++n)
#pragma unroll
          for (int i = 0; i < 4; ++i)
            if (n * 16 + l15 > w * 16 + lg * 4 + i) sfr[n][i] = -1e30f;
      }

      // online softmax (base-2 domain; scale folded into Q)
      float escale[4];
#pragma unroll
      for (int i = 0; i < 4; ++i) {
        float mx = fmaxf(fmaxf(sfr[0][i], sfr[1][i]), fmaxf(sfr[2][i], sfr[3][i]));
        mx = fmaxf(mx, __shfl_xor(mx, 1, 64));
        mx = fmaxf(mx, __shfl_xor(mx, 2, 64));
        mx = fmaxf(mx, __shfl_xor(mx, 4, 64));
        mx = fmaxf(mx, __shfl_xor(mx, 8, 64));
        const float mnew = fmaxf(mrow[i], mx);
        escale[i] = exp2f(mrow[i] - mnew);
        mrow[i] = mnew;
        const int prow = lg * 4 + i;
        float rs = 0.0f;
#pragma unroll
        for (int n = 0; n < 4; ++n) {
          const float p = exp2f(sfr[n][i] - mnew);
          rs += p;
          Ps[w][prow * 64 + (((2 * n + (l15 >> 3)) ^ (prow & 7)) * 8) + sw] = f2bf(p);
        }
        rs += __shfl_xor(rs, 1, 64);
        rs += __shfl_xor(rs, 2, 64);
        rs += __shfl_xor(rs, 4, 64);
        rs += __shfl_xor(rs, 8, 64);
        lrow[i] = lrow[i] * escale[i] + rs;
      }
#pragma unroll
      for (int f = 0; f < 8; ++f)
#pragma unroll
        for (int i = 0; i < 4; ++i) o[f][i] *= escale[i];

      // P is wave-private: no barrier, just drain LDS writes
      asm volatile("s_waitcnt lgkmcnt(0)" ::: "memory");
      __builtin_amdgcn_sched_barrier(0);

      bf16x8 pf[2];
#pragma unroll
      for (int kk = 0; kk < 2; ++kk)
        pf[kk] = *(const bf16x8*)&Ps[w][l15 * 64 + ((kk * 4 + lg) ^ sw) * 8];
#pragma unroll
      for (int f = 0; f < 8; ++f)
#pragma unroll
        for (int kk = 0; kk < 2; ++kk) {
          bf16x8 vf = *(const bf16x8*)&vsb[(f * 16 + l15) * 64 + ((kk * 4 + lg) ^ sw) * 8];
          o[f] = __builtin_amdgcn_mfma_f32_16x16x32_bf16(pf[kk], vf, o[f], 0, 0, 0);
        }

      __syncthreads();  // reads of buf[cur] done; stage into buf[cur^1] drained
    }

#pragma unroll
    for (int i = 0; i < 4; ++i) {
      const float inv = 1.0f / lrow[i];
      const int trow = qrow + lg * 4 + i;
#pragma unroll
      for (int f = 0; f < 8; ++f)
        O[(size_t)trow * HID + h * HD + f * 16 + l15] = f2bf(o[f][i] * inv);
    }
  }
}

// ------------------------------------------------------------------- launch
extern "C" void kernel_launch(void* const* d_in, const int* in_sizes, int n_in,
                              void* d_out, int out_size, void* d_ws, size_t ws_size,
                              hipStream_t stream) {
  const float* hidden = (const float*)d_in[1];
  const float* w_qkv  = (const float*)d_in[2];
  const float* w_o    = (const float*)d_in[3];
  const float* qw     = (const float*)d_in[4];
  const float* qb     = (const float*)d_in[5];
  const float* kw     = (const float*)d_in[6];
  const float* kb     = (const float*)d_in[7];

  char* ws = (char*)d_ws;
  // region A (100663296 B): w_qkv_bf16 during GEMM1; then attn_bf16 + w_o_bf16
  unsigned short* wqkv_bf = (unsigned short*)(ws + 0);
  unsigned short* attn_bf = (unsigned short*)(ws + 0);
  unsigned short* wo_bf   = (unsigned short*)(ws + 16777216);
  // region B (16777216 B): hidden_bf16 during GEMM1; then vt
  unsigned short* hid_bf  = (unsigned short*)(ws + 100663296);
  unsigned short* vt_bf   = (unsigned short*)(ws + 100663296);
  // region C: qkv f32
  float* qkv_f32          = (float*)(ws + 117440512);
  // region D: q,k,v bf16
  unsigned short* q_bf    = (unsigned short*)(ws + 218103808);
  unsigned short* k_bf    = (unsigned short*)(ws + 234881024);
  unsigned short* v_bf    = (unsigned short*)(ws + 251658240);

  cast_bf16<<<2048, 256, 0, stream>>>(hidden, hid_bf, (T_SEQ * HID) / 4);
  cast_bf16<<<2048, 256, 0, stream>>>(w_qkv, wqkv_bf, (QKVW * HID) / 4);
  // GEMM1: M=2048 (MT=16), N=12288 (NT=48) -> 768 blocks (3 full CU-rounds)
  gemm_bt<<<768, 512, 0, stream>>>(hid_bf, wqkv_bf, qkv_f32, T_SEQ, QKVW, HID, 16);
  cast_bf16<<<2048, 256, 0, stream>>>(w_o, wo_bf, (HID * HID) / 4);
  norm_rope<<<T_SEQ, 256, 0, stream>>>(qkv_f32, qw, qb, kw, kb, q_bf, k_bf, v_bf);
  transpose_v<<<dim3(T_SEQ / 64, HD / 64, NH), 256, 0, stream>>>(v_bf, vt_bf);
  attn_fwd<<<dim3(16, NH), 256, 0, stream>>>(q_bf, k_bf, vt_bf, attn_bf);
  // GEMM2: M=2048 (MT=16), N=4096 (NT=16) -> 256 blocks (1 full CU-round)
  gemm_bt<<<256, 512, 0, stream>>>(attn_bf, wo_bf, (float*)d_out, T_SEQ, HID, HID, 16);
}